// Round 2
// baseline (3189.479 us; speedup 1.0000x reference)
//
#include <hip/hip_runtime.h>
#include <hip/hip_bf16.h>

// ProjectedCGCraig on MI355X (gfx950).
// Math reformulation (reference solvers converge to the exact solutions):
//   x = A^T (A A^T)^{-1} b
//   d = projected CG on B with exact projection P v = v - A^T G^{-1} A v,
//       G = A A^T (512x512), G^{-1} applied via fp32 Newton-Schulz inverse X
//       + 2 steps of fp64 iterative refinement (robust to any X error).
// All length-512 solves, matvec dots, and CG scalars accumulate in fp64;
// big vectors/matrices stay fp32. Final d is re-projected to strip drift.
// Sizes fixed by the problem: M=512, N=4096.

#define Mrows 512
#define Ncols 4096

__device__ __forceinline__ float waveReduceF(float v) {
#pragma unroll
  for (int off = 32; off; off >>= 1) v += __shfl_down(v, off, 64);
  return v;
}
__device__ __forceinline__ double waveReduceD(double v) {
#pragma unroll
  for (int off = 32; off; off >>= 1) v += __shfl_down(v, off, 64);
  return v;
}

// ---------------------------------------------------------------------------
// G = A * A^T (512x512, K=4096). Grid (16,16), block 256. Zero-inits scalf[0].
// ---------------------------------------------------------------------------
__global__ __launch_bounds__(256) void k_gemm_aat(const float* __restrict__ A,
                                                  float* __restrict__ G,
                                                  float* __restrict__ scalf) {
  __shared__ float Ai[32][33], Aj[32][33];
  const int tid = threadIdx.x;
  const int tx = tid & 15, ty = tid >> 4;
  const int bi = blockIdx.y * 32, bj = blockIdx.x * 32;
  const int r0 = ty * 2, c0 = tx * 2;
  float acc00 = 0.f, acc01 = 0.f, acc10 = 0.f, acc11 = 0.f;
  for (int k0 = 0; k0 < Ncols; k0 += 32) {
#pragma unroll
    for (int l = 0; l < 4; l++) {
      int e = tid + l * 256;
      int rr = e >> 5, cc = e & 31;
      Ai[rr][cc] = A[(size_t)(bi + rr) * Ncols + k0 + cc];
      Aj[rr][cc] = A[(size_t)(bj + rr) * Ncols + k0 + cc];
    }
    __syncthreads();
#pragma unroll
    for (int kk = 0; kk < 32; kk++) {
      float a0 = Ai[r0][kk], a1 = Ai[r0 + 1][kk];
      float b0 = Aj[c0][kk], b1 = Aj[c0 + 1][kk];
      acc00 += a0 * b0; acc01 += a0 * b1;
      acc10 += a1 * b0; acc11 += a1 * b1;
    }
    __syncthreads();
  }
  size_t o = (size_t)(bi + r0) * Mrows + bj + c0;
  G[o] = acc00; G[o + 1] = acc01; G[o + Mrows] = acc10; G[o + Mrows + 1] = acc11;
  if (bi == 0 && bj == 0 && tid == 0) scalf[0] = 0.f;
}

// Gershgorin bound: scalf[0] = max_i sum_j |G[i][j]| (int-atomicMax trick, positives)
__global__ void k_gersh(const float* __restrict__ G, float* __restrict__ scalf) {
  const int m = blockIdx.x, tid = threadIdx.x;
  float acc = 0.f;
  for (int j = tid; j < Mrows; j += 64) acc += fabsf(G[m * Mrows + j]);
  acc = waveReduceF(acc);
  if (tid == 0) atomicMax((int*)&scalf[0], __float_as_int(acc));
}

// X = (1/lambda) * I ; zero rz + flag
__global__ void k_init_x(float* __restrict__ X, const float* __restrict__ scalf,
                         double* __restrict__ scald, int* __restrict__ flag) {
  float inv = 1.f / scalf[0];
  int idx = blockIdx.x * blockDim.x + threadIdx.x;  // 65536 threads
#pragma unroll
  for (int l = 0; l < 4; l++) {
    int e = idx + l * 65536;
    X[e] = ((e >> 9) == (e & 511)) ? inv : 0.f;
  }
  if (idx == 0) { scald[1] = 0.0; flag[0] = 0; }
}

// 512x512x512 GEMM. mode 0: C = Am*Bm. mode 1: C = 2*Dm - Am*Bm (Newton step).
__global__ __launch_bounds__(256) void k_gemm512(float* __restrict__ C,
                                                 const float* __restrict__ Am,
                                                 const float* __restrict__ Bm,
                                                 const float* __restrict__ Dm,
                                                 int mode) {
  __shared__ float As[32][33], Bs[32][33];
  const int tid = threadIdx.x;
  const int tx = tid & 15, ty = tid >> 4;
  const int bi = blockIdx.y * 32, bj = blockIdx.x * 32;
  const int r0 = ty * 2, c0 = tx * 2;
  float acc00 = 0.f, acc01 = 0.f, acc10 = 0.f, acc11 = 0.f;
  for (int k0 = 0; k0 < Mrows; k0 += 32) {
#pragma unroll
    for (int l = 0; l < 4; l++) {
      int e = tid + l * 256;
      int rr = e >> 5, cc = e & 31;
      As[rr][cc] = Am[(size_t)(bi + rr) * Mrows + k0 + cc];
      Bs[rr][cc] = Bm[(size_t)(k0 + rr) * Mrows + bj + cc];
    }
    __syncthreads();
#pragma unroll
    for (int kk = 0; kk < 32; kk++) {
      float a0 = As[r0][kk], a1 = As[r0 + 1][kk];
      float b0 = Bs[kk][c0], b1 = Bs[kk][c0 + 1];
      acc00 += a0 * b0; acc01 += a0 * b1;
      acc10 += a1 * b0; acc11 += a1 * b1;
    }
    __syncthreads();
  }
  size_t o = (size_t)(bi + r0) * Mrows + bj + c0;
  if (mode == 1) {
    acc00 = 2.f * Dm[o] - acc00;
    acc01 = 2.f * Dm[o + 1] - acc01;
    acc10 = 2.f * Dm[o + Mrows] - acc10;
    acc11 = 2.f * Dm[o + Mrows + 1] - acc11;
  }
  C[o] = acc00; C[o + 1] = acc01; C[o + Mrows] = acc10; C[o + Mrows + 1] = acc11;
}

// ---------------------------------------------------------------------------
// t1d[m] = dot(A[m,:], v) in fp64. Grid 512 blocks x 256.
// zero_pp: block 0 zeroes scald[2], scald[3].  chk: honor flag.
// ---------------------------------------------------------------------------
__global__ __launch_bounds__(256) void k_mv_A(const float* __restrict__ A,
                                              const float* __restrict__ v,
                                              double* __restrict__ t1d,
                                              double* __restrict__ scald,
                                              const int* __restrict__ flag,
                                              int zero_pp, int chk) {
  if (chk && *flag) return;
  const int m = blockIdx.x, tid = threadIdx.x;
  const float4* Mr = (const float4*)(A + (size_t)m * Ncols);
  const float4* v4 = (const float4*)v;
  double acc = 0.0;
#pragma unroll
  for (int i = 0; i < 4; i++) {
    float4 a = Mr[tid + 256 * i];
    float4 x = v4[tid + 256 * i];
    acc += (double)a.x * x.x + (double)a.y * x.y + (double)a.z * x.z + (double)a.w * x.w;
  }
  __shared__ double sb[4];
  acc = waveReduceD(acc);
  const int lane = tid & 63, wid = tid >> 6;
  if (!lane) sb[wid] = acc;
  __syncthreads();
  if (!tid) {
    t1d[m] = sb[0] + sb[1] + sb[2] + sb[3];
    if (m == 0 && zero_pp) { scald[2] = 0.0; scald[3] = 0.0; }
  }
}

// Bp[m] = dot(B[m,:], p) in fp64, stored fp32. Grid 4096 blocks x 256.
__global__ __launch_bounds__(256) void k_mv_B(const float* __restrict__ B,
                                              const float* __restrict__ p,
                                              float* __restrict__ Bp,
                                              const int* __restrict__ flag) {
  if (*flag) return;
  const int m = blockIdx.x, tid = threadIdx.x;
  const float4* Mr = (const float4*)(B + (size_t)m * Ncols);
  const float4* v4 = (const float4*)p;
  double acc = 0.0;
#pragma unroll
  for (int i = 0; i < 4; i++) {
    float4 a = Mr[tid + 256 * i];
    float4 x = v4[tid + 256 * i];
    acc += (double)a.x * x.x + (double)a.y * x.y + (double)a.z * x.z + (double)a.w * x.w;
  }
  __shared__ double sb[4];
  acc = waveReduceD(acc);
  const int lane = tid & 63, wid = tid >> 6;
  if (!lane) sb[wid] = acc;
  __syncthreads();
  if (!tid) Bp[m] = (float)(sb[0] + sb[1] + sb[2] + sb[3]);
}

// ---------------------------------------------------------------------------
// Solve G y = rhs:  y = X rhs, then 2 rounds of fp64 iterative refinement
//   y += X (rhs - G y).  One block, 512 threads. rhs from fp32 or fp64 ptr.
// Fixed point is exactly G y = rhs regardless of X's error/asymmetry.
// G/X read by columns (coalesced); G is exactly symmetric by construction.
// ---------------------------------------------------------------------------
__global__ __launch_bounds__(512) void k_ysolve(const float* __restrict__ G,
                                                const float* __restrict__ X,
                                                const float* __restrict__ rhs_f,
                                                const double* __restrict__ rhs_d,
                                                double* __restrict__ y_out,
                                                const int* __restrict__ flag, int chk) {
  if (chk && *flag) return;
  __shared__ double rs[512], ys[512], wsm[512];
  const int i = threadIdx.x;
  rs[i] = rhs_f ? (double)rhs_f[i] : rhs_d[i];
  __syncthreads();
  double y = 0.0;
  for (int k = 0; k < Mrows; k++) y += (double)X[k * Mrows + i] * rs[k];
  ys[i] = y;
  __syncthreads();
#pragma unroll
  for (int rf = 0; rf < 2; rf++) {
    double w = rs[i];
    for (int k = 0; k < Mrows; k++) w -= (double)G[k * Mrows + i] * ys[k];
    wsm[i] = w;
    __syncthreads();
    double dy = 0.0;
    for (int k = 0; k < Mrows; k++) dy += (double)X[k * Mrows + i] * wsm[k];
    y += dy;
    __syncthreads();
    ys[i] = y;
    __syncthreads();
  }
  y_out[i] = y;
}

// ---------------------------------------------------------------------------
// Setup outputs + CG init (grid 16 x 256):
//   x = A^T y0 -> out[0..4096) ;  r = p = A^T y1 - g ; dv = 0 ; rz += ||r||^2
// ---------------------------------------------------------------------------
__global__ __launch_bounds__(256) void k_setup_fin(const float* __restrict__ A,
                                                   const double* __restrict__ y0d,
                                                   const double* __restrict__ y1d,
                                                   const float* __restrict__ g,
                                                   float* __restrict__ out,
                                                   float* __restrict__ r,
                                                   float* __restrict__ p,
                                                   float* __restrict__ dv,
                                                   double* __restrict__ scald) {
  __shared__ double y0s[512], y1s[512];
  const int tid = threadIdx.x;
  y0s[tid] = y0d[tid]; y0s[tid + 256] = y0d[tid + 256];
  y1s[tid] = y1d[tid]; y1s[tid + 256] = y1d[tid + 256];
  __syncthreads();
  const int col = blockIdx.x * 256 + tid;
  double xa = 0.0, ra = 0.0;
  for (int m = 0; m < Mrows; m++) {
    double av = (double)A[(size_t)m * Ncols + col];
    xa += av * y0s[m];
    ra += av * y1s[m];
  }
  out[col] = (float)xa;
  float rv = (float)(ra - (double)g[col]);
  r[col] = rv; p[col] = rv; dv[col] = 0.f;
  double acc = waveReduceD((double)rv * rv);
  __shared__ double sb[4];
  const int lane = tid & 63, wid = tid >> 6;
  if (!lane) sb[wid] = acc;
  __syncthreads();
  if (!tid) atomicAdd(&scald[1], sb[0] + sb[1] + sb[2] + sb[3]);
}

// ---------------------------------------------------------------------------
// PBp = Bp - A^T y ; pPBp += p.PBp ; pp += p.p  (grid 16 x 256, fp64 dots)
// ---------------------------------------------------------------------------
__global__ __launch_bounds__(256) void k_pcc2(const float* __restrict__ A,
                                              const double* __restrict__ yd,
                                              const float* __restrict__ Bp,
                                              const float* __restrict__ p,
                                              float* __restrict__ PBp,
                                              double* __restrict__ scald,
                                              const int* __restrict__ flag) {
  if (*flag) return;
  __shared__ double ysm[512];
  const int tid = threadIdx.x;
  ysm[tid] = yd[tid]; ysm[tid + 256] = yd[tid + 256];
  __syncthreads();
  const int col = blockIdx.x * 256 + tid;
  double acc = 0.0;
  for (int m = 0; m < Mrows; m++) acc += (double)A[(size_t)m * Ncols + col] * ysm[m];
  double pb = (double)Bp[col] - acc;
  PBp[col] = (float)pb;
  double pi = (double)p[col];
  double v1 = waveReduceD(pi * pb);
  double v2 = waveReduceD(pi * pi);
  __shared__ double s1[4], s2[4];
  const int lane = tid & 63, wid = tid >> 6;
  if (!lane) { s1[wid] = v1; s2[wid] = v2; }
  __syncthreads();
  if (!tid) {
    atomicAdd(&scald[2], s1[0] + s1[1] + s1[2] + s1[3]);
    atomicAdd(&scald[3], s2[0] + s2[1] + s2[2] + s2[3]);
  }
}

// ---------------------------------------------------------------------------
// CG scalar + vector update (1 block, 256 threads), fp64 scalars.
// ---------------------------------------------------------------------------
__global__ __launch_bounds__(256) void k_cg_up(float* __restrict__ dv,
                                               float* __restrict__ r,
                                               float* __restrict__ p,
                                               const float* __restrict__ PBp,
                                               double* __restrict__ scald,
                                               int* __restrict__ flag) {
  if (*flag) return;
  const int tid = threadIdx.x;
  const double rz = scald[1], pPBp = scald[2], pp = scald[3];
  const bool bad = (pPBp <= 1e-6 * pp);
  if (bad) { if (!tid) *flag = 1; return; }
  const double alpha = rz / fmax(pPBp, 1e-300);
  float rn[16], pold[16];
  double acc = 0.0;
#pragma unroll
  for (int i = 0; i < 16; i++) {
    int idx = tid + 256 * i;
    float pi = p[idx]; pold[i] = pi;
    dv[idx] = (float)((double)dv[idx] + alpha * (double)pi);
    float rv = (float)((double)r[idx] - alpha * (double)PBp[idx]);
    r[idx] = rv; rn[i] = rv;
    acc += (double)rv * rv;
  }
  __shared__ double sb[4];
  __shared__ double s_rn2;
  acc = waveReduceD(acc);
  const int lane = tid & 63, wid = tid >> 6;
  if (!lane) sb[wid] = acc;
  __syncthreads();
  if (!tid) s_rn2 = sb[0] + sb[1] + sb[2] + sb[3];
  __syncthreads();
  const double rn2 = s_rn2;
  const double beta = rn2 / fmax(rz, 1e-300);
#pragma unroll
  for (int i = 0; i < 16; i++) {
    int idx = tid + 256 * i;
    p[idx] = (float)((double)rn[i] + beta * (double)pold[i]);
  }
  if (!tid) {
    scald[1] = rn2;
    if (rn2 < 1e-16) *flag = 1;
  }
}

// Final: out[4096+col] = dv[col] - (A^T yd)[col]   (re-project d)
__global__ __launch_bounds__(256) void k_final_d(const float* __restrict__ A,
                                                 const double* __restrict__ yd,
                                                 const float* __restrict__ dv,
                                                 float* __restrict__ out) {
  __shared__ double ysm[512];
  const int tid = threadIdx.x;
  ysm[tid] = yd[tid]; ysm[tid + 256] = yd[tid + 256];
  __syncthreads();
  const int col = blockIdx.x * 256 + tid;
  double acc = 0.0;
  for (int m = 0; m < Mrows; m++) acc += (double)A[(size_t)m * Ncols + col] * ysm[m];
  out[Ncols + col] = (float)((double)dv[col] - acc);
}

// ---------------------------------------------------------------------------
extern "C" void kernel_launch(void* const* d_in, const int* in_sizes, int n_in,
                              void* d_out, int out_size, void* d_ws, size_t ws_size,
                              hipStream_t stream) {
  const float* A = (const float*)d_in[0];   // 512 x 4096
  const float* b = (const float*)d_in[1];   // 512
  const float* B = (const float*)d_in[2];   // 4096 x 4096
  const float* g = (const float*)d_in[3];   // 4096
  float* out = (float*)d_out;               // x[4096] then d[4096]
  char* w = (char*)d_ws;

  float*  G    = (float*)(w);             // 1 MB
  float*  Xa   = (float*)(w + 1048576);   // 1 MB
  float*  Xb   = (float*)(w + 2097152);   // 1 MB
  float*  T    = (float*)(w + 3145728);   // 1 MB
  float*  Bp   = (float*)(w + 4194304);   // 16 KB
  float*  PBp  = (float*)(w + 4210688);
  float*  r    = (float*)(w + 4227072);
  float*  p    = (float*)(w + 4243456);
  float*  dv   = (float*)(w + 4259840);
  double* t1d  = (double*)(w + 4276224);  // 4 KB
  double* y0d  = (double*)(w + 4280320);
  double* y1d  = (double*)(w + 4284416);  // also reused as yd in CG loop
  double* scald = (double*)(w + 4288512); // [1]=rz [2]=pPBp [3]=pp
  float*  scalf = (float*)(w + 4288576);  // [0]=lambda
  int*    flag  = (int*)(w + 4288608);

  // --- setup: G = A A^T, Gershgorin, fp32 Newton-Schulz inverse (11 iters) ---
  k_gemm_aat<<<dim3(16, 16), 256, 0, stream>>>(A, G, scalf);
  k_gersh<<<Mrows, 64, 0, stream>>>(G, scalf);
  k_init_x<<<256, 256, 0, stream>>>(Xa, scalf, scald, flag);
  float* Xcur = Xa;
  float* Xnxt = Xb;
  for (int it = 0; it < 11; it++) {
    k_gemm512<<<dim3(16, 16), 256, 0, stream>>>(T, G, Xcur, (const float*)0, 0);
    k_gemm512<<<dim3(16, 16), 256, 0, stream>>>(Xnxt, Xcur, T, Xcur, 1);
    float* tmp = Xcur; Xcur = Xnxt; Xnxt = tmp;
  }

  // --- x = A^T G^{-1} b ; r0 = p = A^T G^{-1} (A g) - g ; rz = ||r0||^2 ---
  k_mv_A<<<Mrows, 256, 0, stream>>>(A, g, t1d, scald, flag, 0, 0);
  k_ysolve<<<1, 512, 0, stream>>>(G, Xcur, b, (const double*)0, y0d, flag, 0);
  k_ysolve<<<1, 512, 0, stream>>>(G, Xcur, (const float*)0, t1d, y1d, flag, 0);
  k_setup_fin<<<16, 256, 0, stream>>>(A, y0d, y1d, g, out, r, p, dv, scald);

  // --- projected CG, 25 iterations (reference fori_loop bound) ---
  for (int it = 0; it < 25; it++) {
    k_mv_B<<<Ncols, 256, 0, stream>>>(B, p, Bp, flag);                      // Bp = B p
    k_mv_A<<<Mrows, 256, 0, stream>>>(A, Bp, t1d, scald, flag, 1, 1);       // t1 = A Bp
    k_ysolve<<<1, 512, 0, stream>>>(G, Xcur, (const float*)0, t1d, y1d, flag, 1);
    k_pcc2<<<16, 256, 0, stream>>>(A, y1d, Bp, p, PBp, scald, flag);
    k_cg_up<<<1, 256, 0, stream>>>(dv, r, p, PBp, scald, flag);
  }

  // --- d_out = P(dv) : strip any row-space contamination ---
  k_mv_A<<<Mrows, 256, 0, stream>>>(A, dv, t1d, scald, flag, 0, 0);
  k_ysolve<<<1, 512, 0, stream>>>(G, Xcur, (const float*)0, t1d, y1d, flag, 0);
  k_final_d<<<16, 256, 0, stream>>>(A, y1d, dv, out);
}

// Round 4
// 1196.795 us; speedup vs baseline: 2.6650x; 2.6650x over previous
//
#include <hip/hip_runtime.h>
#include <hip/hip_bf16.h>

// ProjectedCGCraig on MI355X (gfx950).
//   x = A^T G^{-1} b,  G = A A^T (512x512)
//   d = projected CG (25 iters) with P v = v - A^T G^{-1} A v
// LESSON (R3): the per-iteration projection solve MUST be refinement-exact
// (fp64 residual, ~1e-12); the fp32 W=X*A operator (~1e-4) fails at the 2%
// threshold because post-stagnation CG random-walks at the projection-noise
// scale. So every G-solve = X-apply + 2 fp64-refinement rounds (exact fixed
// point of G y = rhs regardless of X error), done as parallel matvec chains.
// M=512, N=4096 fixed.

#define Mrows 512
#define Ncols 4096

__device__ __forceinline__ float waveReduceF(float v) {
#pragma unroll
  for (int off = 32; off; off >>= 1) v += __shfl_down(v, off, 64);
  return v;
}
__device__ __forceinline__ double waveReduceD(double v) {
#pragma unroll
  for (int off = 32; off; off >>= 1) v += __shfl_down(v, off, 64);
  return v;
}

// ---------------------------------------------------------------------------
// Generic tiled GEMM, row-major: C = Am[M x K] * Bm[K x N].
// 64x64 tile, 4x4 microtile, 256 threads. grid (N/64, M/64, S) with K-split S;
// slice z writes Cp + z*part_stride.
// ---------------------------------------------------------------------------
__global__ __launch_bounds__(256) void k_gemm_t(const float* __restrict__ Am,
                                                const float* __restrict__ Bm,
                                                float* __restrict__ Cp,
                                                int K, int N, int part_stride) {
  __shared__ float At[32][68];  // [k][row]
  __shared__ float Bt[32][68];  // [k][col]
  const int tid = threadIdx.x;
  const int tx = tid & 15, ty = tid >> 4;
  const int bj = blockIdx.x * 64, bi = blockIdx.y * 64;
  const int Klen = K / gridDim.z;
  const int Kb = blockIdx.z * Klen;
  float c0x = 0.f, c0y = 0.f, c0z = 0.f, c0w = 0.f;
  float c1x = 0.f, c1y = 0.f, c1z = 0.f, c1w = 0.f;
  float c2x = 0.f, c2y = 0.f, c2z = 0.f, c2w = 0.f;
  float c3x = 0.f, c3y = 0.f, c3z = 0.f, c3w = 0.f;
  for (int k0 = 0; k0 < Klen; k0 += 32) {
#pragma unroll
    for (int l = 0; l < 2; l++) {
      int f = tid + l * 256;
      int ar = f >> 3, ak = f & 7;
      const float4 av = *(const float4*)&Am[(size_t)(bi + ar) * K + Kb + k0 + ak * 4];
      At[ak * 4 + 0][ar] = av.x; At[ak * 4 + 1][ar] = av.y;
      At[ak * 4 + 2][ar] = av.z; At[ak * 4 + 3][ar] = av.w;
    }
#pragma unroll
    for (int l = 0; l < 2; l++) {
      int f = tid + l * 256;
      int br = f >> 4, bc = f & 15;
      *(float4*)&Bt[br][bc * 4] =
          *(const float4*)&Bm[(size_t)(Kb + k0 + br) * N + bj + bc * 4];
    }
    __syncthreads();
#pragma unroll
    for (int kk = 0; kk < 32; kk++) {
      float4 a = *(float4*)&At[kk][ty * 4];
      float4 b = *(float4*)&Bt[kk][tx * 4];
      c0x += a.x * b.x; c0y += a.x * b.y; c0z += a.x * b.z; c0w += a.x * b.w;
      c1x += a.y * b.x; c1y += a.y * b.y; c1z += a.y * b.z; c1w += a.y * b.w;
      c2x += a.z * b.x; c2y += a.z * b.y; c2z += a.z * b.z; c2w += a.z * b.w;
      c3x += a.w * b.x; c3y += a.w * b.y; c3z += a.w * b.z; c3w += a.w * b.w;
    }
    __syncthreads();
  }
  float* Co = Cp + (size_t)blockIdx.z * part_stride;
  size_t o = (size_t)(bi + ty * 4) * N + bj + tx * 4;
  *(float4*)&Co[o]         = make_float4(c0x, c0y, c0z, c0w);
  *(float4*)&Co[o + N]     = make_float4(c1x, c1y, c1z, c1w);
  *(float4*)&Co[o + 2 * N] = make_float4(c2x, c2y, c2z, c2w);
  *(float4*)&Co[o + 3 * N] = make_float4(c3x, c3y, c3z, c3w);
}

// ---------------------------------------------------------------------------
// Partial AAT: slice bz computes A[bi..][Kb..] * A[bj..][Kb..]^T, K-slice 512.
// grid (8,8,8). Deterministic reduce keeps G exactly symmetric.
// ---------------------------------------------------------------------------
__global__ __launch_bounds__(256) void k_aat_part(const float* __restrict__ A,
                                                  float* __restrict__ P) {
  __shared__ float At[32][68];
  __shared__ float Bt[32][68];
  const int tid = threadIdx.x;
  const int tx = tid & 15, ty = tid >> 4;
  const int bj = blockIdx.x * 64, bi = blockIdx.y * 64;
  const int Kb = blockIdx.z * 512;
  float c0x = 0.f, c0y = 0.f, c0z = 0.f, c0w = 0.f;
  float c1x = 0.f, c1y = 0.f, c1z = 0.f, c1w = 0.f;
  float c2x = 0.f, c2y = 0.f, c2z = 0.f, c2w = 0.f;
  float c3x = 0.f, c3y = 0.f, c3z = 0.f, c3w = 0.f;
  for (int k0 = 0; k0 < 512; k0 += 32) {
#pragma unroll
    for (int l = 0; l < 2; l++) {
      int f = tid + l * 256;
      int ar = f >> 3, ak = f & 7;
      const float4 av = *(const float4*)&A[(size_t)(bi + ar) * Ncols + Kb + k0 + ak * 4];
      At[ak * 4 + 0][ar] = av.x; At[ak * 4 + 1][ar] = av.y;
      At[ak * 4 + 2][ar] = av.z; At[ak * 4 + 3][ar] = av.w;
      const float4 bv = *(const float4*)&A[(size_t)(bj + ar) * Ncols + Kb + k0 + ak * 4];
      Bt[ak * 4 + 0][ar] = bv.x; Bt[ak * 4 + 1][ar] = bv.y;
      Bt[ak * 4 + 2][ar] = bv.z; Bt[ak * 4 + 3][ar] = bv.w;
    }
    __syncthreads();
#pragma unroll
    for (int kk = 0; kk < 32; kk++) {
      float4 a = *(float4*)&At[kk][ty * 4];
      float4 b = *(float4*)&Bt[kk][tx * 4];
      c0x += a.x * b.x; c0y += a.x * b.y; c0z += a.x * b.z; c0w += a.x * b.w;
      c1x += a.y * b.x; c1y += a.y * b.y; c1z += a.y * b.z; c1w += a.y * b.w;
      c2x += a.z * b.x; c2y += a.z * b.y; c2z += a.z * b.z; c2w += a.z * b.w;
      c3x += a.w * b.x; c3y += a.w * b.y; c3z += a.w * b.z; c3w += a.w * b.w;
    }
    __syncthreads();
  }
  float* Co = P + (size_t)blockIdx.z * 262144;
  size_t o = (size_t)(bi + ty * 4) * Mrows + bj + tx * 4;
  *(float4*)&Co[o]             = make_float4(c0x, c0y, c0z, c0w);
  *(float4*)&Co[o + Mrows]     = make_float4(c1x, c1y, c1z, c1w);
  *(float4*)&Co[o + 2 * Mrows] = make_float4(c2x, c2y, c2z, c2w);
  *(float4*)&Co[o + 3 * Mrows] = make_float4(c3x, c3y, c3z, c3w);
}

// G = sum of 8 partials; also zero scalf[0]/scald[1]/flag.
__global__ void k_red_G(const float* __restrict__ P, float* __restrict__ G,
                        float* __restrict__ scalf, double* __restrict__ scald,
                        int* __restrict__ flag) {
  int i4 = blockIdx.x * 256 + threadIdx.x;  // 65536 float4s
  float4 s = ((const float4*)P)[i4];
#pragma unroll
  for (int p = 1; p < 8; p++) {
    float4 v = ((const float4*)(P + (size_t)p * 262144))[i4];
    s.x += v.x; s.y += v.y; s.z += v.z; s.w += v.w;
  }
  ((float4*)G)[i4] = s;
  if (i4 == 0) { scalf[0] = 0.f; scald[1] = 0.0; flag[0] = 0; }
}

// mode 0: dst = P0+P1+P2+P3 ; mode 1: dst = 2*D - (P0+P1+P2+P3)
__global__ void k_red4(float* __restrict__ dst, const float* __restrict__ P,
                       const float* __restrict__ D, int mode) {
  int i4 = blockIdx.x * 256 + threadIdx.x;
  float4 s = ((const float4*)P)[i4];
#pragma unroll
  for (int p = 1; p < 4; p++) {
    float4 v = ((const float4*)(P + (size_t)p * 262144))[i4];
    s.x += v.x; s.y += v.y; s.z += v.z; s.w += v.w;
  }
  if (mode == 1) {
    float4 d = ((const float4*)D)[i4];
    s = make_float4(2.f * d.x - s.x, 2.f * d.y - s.y, 2.f * d.z - s.z, 2.f * d.w - s.w);
  }
  ((float4*)dst)[i4] = s;
}

// Gershgorin bound: scalf[0] = max_i sum_j |G[i][j]|
__global__ void k_gersh(const float* __restrict__ G, float* __restrict__ scalf) {
  const int m = blockIdx.x, tid = threadIdx.x;
  float acc = 0.f;
  for (int j = tid; j < Mrows; j += 64) acc += fabsf(G[m * Mrows + j]);
  acc = waveReduceF(acc);
  if (tid == 0) atomicMax((int*)&scalf[0], __float_as_int(acc));
}

// X0 = (2/lambda) * I  (spectrum of X0*G in (0,1) since Gershgorin >= lmax)
__global__ void k_init_x(float* __restrict__ X, const float* __restrict__ scalf) {
  float inv = 2.f / scalf[0];
  int idx = blockIdx.x * blockDim.x + threadIdx.x;
#pragma unroll
  for (int l = 0; l < 4; l++) {
    int e = idx + l * 65536;
    X[e] = ((e >> 9) == (e & 511)) ? inv : 0.f;
  }
}

// ---------------------------------------------------------------------------
// 512-dim fp64 matvec for refinement solves. 512 blocks x 64 threads.
// mode 0: y[m]  = dot(Mat[m,:], v)          (v = rhs, f32 or f64)
// mode 1: y[m]  = r2[m] - dot(Mat[m,:], v)  (residual; r2 f32 or f64, v f64)
// mode 2: y[m] += dot(Mat[m,:], v)          (correction; v f64)
// ---------------------------------------------------------------------------
__global__ __launch_bounds__(64) void k_gmv_d(const float* __restrict__ Mat,
                                              const float* __restrict__ vf,
                                              const double* __restrict__ vd,
                                              const float* __restrict__ r2f,
                                              const double* __restrict__ r2d,
                                              double* __restrict__ y, int mode) {
  const int m = blockIdx.x, t = threadIdx.x;
  const float4* Mr = (const float4*)(Mat + (size_t)m * Mrows);
  double acc = 0.0;
#pragma unroll
  for (int l = 0; l < 2; l++) {
    int i4 = t + l * 64;
    float4 a = Mr[i4];
    double x0, x1, x2, x3;
    if (vf) {
      float4 v = ((const float4*)vf)[i4];
      x0 = v.x; x1 = v.y; x2 = v.z; x3 = v.w;
    } else {
      x0 = vd[i4 * 4]; x1 = vd[i4 * 4 + 1]; x2 = vd[i4 * 4 + 2]; x3 = vd[i4 * 4 + 3];
    }
    acc += (double)a.x * x0 + (double)a.y * x1 + (double)a.z * x2 + (double)a.w * x3;
  }
  acc = waveReduceD(acc);
  if (t == 0) {
    if (mode == 0) y[m] = acc;
    else if (mode == 1) y[m] = (r2f ? (double)r2f[m] : r2d[m]) - acc;
    else y[m] += acc;
  }
}

// t1d[m] = dot(A[m,:], v) fp64, row length 4096. 512 blocks x 256.
__global__ __launch_bounds__(256) void k_mv_A(const float* __restrict__ Mat,
                                              const float* __restrict__ v,
                                              double* __restrict__ t1d,
                                              const int* __restrict__ flag, int chk) {
  if (chk && *flag) return;
  const int m = blockIdx.x, tid = threadIdx.x;
  const float4* Mr = (const float4*)(Mat + (size_t)m * Ncols);
  const float4* v4 = (const float4*)v;
  double acc = 0.0;
#pragma unroll
  for (int i = 0; i < 4; i++) {
    float4 a = Mr[tid + 256 * i];
    float4 x = v4[tid + 256 * i];
    acc += (double)a.x * x.x + (double)a.y * x.y + (double)a.z * x.z + (double)a.w * x.w;
  }
  __shared__ double sb[4];
  acc = waveReduceD(acc);
  const int lane = tid & 63, wid = tid >> 6;
  if (!lane) sb[wid] = acc;
  __syncthreads();
  if (!tid) t1d[m] = sb[0] + sb[1] + sb[2] + sb[3];
}

// Bp[m] = dot(B[m,:], p). 4096 blocks x 256. Block 0 zeroes pPBp/pp accums.
__global__ __launch_bounds__(256) void k_mv_B(const float* __restrict__ B,
                                              const float* __restrict__ p,
                                              float* __restrict__ Bp,
                                              double* __restrict__ scald,
                                              const int* __restrict__ flag) {
  if (*flag) return;
  const int m = blockIdx.x, tid = threadIdx.x;
  const float4* Mr = (const float4*)(B + (size_t)m * Ncols);
  const float4* v4 = (const float4*)p;
  double acc = 0.0;
#pragma unroll
  for (int i = 0; i < 4; i++) {
    float4 a = Mr[tid + 256 * i];
    float4 x = v4[tid + 256 * i];
    acc += (double)a.x * x.x + (double)a.y * x.y + (double)a.z * x.z + (double)a.w * x.w;
  }
  __shared__ double sb[4];
  acc = waveReduceD(acc);
  const int lane = tid & 63, wid = tid >> 6;
  if (!lane) sb[wid] = acc;
  __syncthreads();
  if (!tid) {
    Bp[m] = (float)(sb[0] + sb[1] + sb[2] + sb[3]);
    if (m == 0) { scald[2] = 0.0; scald[3] = 0.0; }
  }
}

// ---------------------------------------------------------------------------
// Setup outputs + CG init (grid 16 x 256):
//   x = A^T y0 -> out[0..4096) ; r = p = A^T y1 - g ; dv = 0 ; rz += ||r||^2
// ---------------------------------------------------------------------------
__global__ __launch_bounds__(256) void k_setup_fin(const float* __restrict__ A,
                                                   const double* __restrict__ y0d,
                                                   const double* __restrict__ y1d,
                                                   const float* __restrict__ g,
                                                   float* __restrict__ out,
                                                   float* __restrict__ r,
                                                   float* __restrict__ p,
                                                   float* __restrict__ dv,
                                                   double* __restrict__ scald) {
  __shared__ double y0s[512], y1s[512];
  const int tid = threadIdx.x;
  y0s[tid] = y0d[tid]; y0s[tid + 256] = y0d[tid + 256];
  y1s[tid] = y1d[tid]; y1s[tid + 256] = y1d[tid + 256];
  __syncthreads();
  const int col = blockIdx.x * 256 + tid;
  double xa = 0.0, ra = 0.0;
  for (int m = 0; m < Mrows; m++) {
    double av = (double)A[(size_t)m * Ncols + col];
    xa += av * y0s[m];
    ra += av * y1s[m];
  }
  out[col] = (float)xa;
  float rv = (float)(ra - (double)g[col]);
  r[col] = rv; p[col] = rv; dv[col] = 0.f;
  double acc = waveReduceD((double)rv * rv);
  __shared__ double sb[4];
  const int lane = tid & 63, wid = tid >> 6;
  if (!lane) sb[wid] = acc;
  __syncthreads();
  if (!tid) atomicAdd(&scald[1], sb[0] + sb[1] + sb[2] + sb[3]);
}

// ---------------------------------------------------------------------------
// PBp = Bp - A^T y ; pPBp += p.PBp ; pp += p.p
// Grid 64 x 256: 64 cols/block, m-loop quarter-split across tid>>6.
// ---------------------------------------------------------------------------
__global__ __launch_bounds__(256) void k_pcc2(const float* __restrict__ A,
                                              const double* __restrict__ yd,
                                              const float* __restrict__ Bp,
                                              const float* __restrict__ p,
                                              float* __restrict__ PBp,
                                              double* __restrict__ scald,
                                              const int* __restrict__ flag) {
  if (*flag) return;
  __shared__ double ysm[512];
  __shared__ double part[4][64];
  const int tid = threadIdx.x;
  ysm[tid] = yd[tid]; ysm[tid + 256] = yd[tid + 256];
  __syncthreads();
  const int cl = tid & 63;     // column within block's 64
  const int q = tid >> 6;      // m-quarter
  const int col = blockIdx.x * 64 + cl;
  double acc = 0.0;
  for (int m = q * 128; m < q * 128 + 128; m++)
    acc += (double)A[(size_t)m * Ncols + col] * ysm[m];
  part[q][cl] = acc;
  __syncthreads();
  if (q == 0) {
    double s = part[0][cl] + part[1][cl] + part[2][cl] + part[3][cl];
    double pb = (double)Bp[col] - s;
    PBp[col] = (float)pb;
    double pi = (double)p[col];
    double v1 = waveReduceD(pi * pb);
    double v2 = waveReduceD(pi * pi);
    if (cl == 0) {
      atomicAdd(&scald[2], v1);
      atomicAdd(&scald[3], v2);
    }
  }
}

// CG scalar + vector update (1 block, 256 threads), fp64 scalars.
__global__ __launch_bounds__(256) void k_cg_up(float* __restrict__ dv,
                                               float* __restrict__ r,
                                               float* __restrict__ p,
                                               const float* __restrict__ PBp,
                                               double* __restrict__ scald,
                                               int* __restrict__ flag) {
  if (*flag) return;
  const int tid = threadIdx.x;
  const double rz = scald[1], pPBp = scald[2], pp = scald[3];
  const bool bad = (pPBp <= 1e-6 * pp);
  if (bad) { if (!tid) *flag = 1; return; }
  const double alpha = rz / fmax(pPBp, 1e-300);
  float rn[16], pold[16];
  double acc = 0.0;
#pragma unroll
  for (int i = 0; i < 16; i++) {
    int idx = tid + 256 * i;
    float pi = p[idx]; pold[i] = pi;
    dv[idx] = (float)((double)dv[idx] + alpha * (double)pi);
    float rv = (float)((double)r[idx] - alpha * (double)PBp[idx]);
    r[idx] = rv; rn[i] = rv;
    acc += (double)rv * rv;
  }
  __shared__ double sb[4];
  __shared__ double s_rn2;
  acc = waveReduceD(acc);
  const int lane = tid & 63, wid = tid >> 6;
  if (!lane) sb[wid] = acc;
  __syncthreads();
  if (!tid) s_rn2 = sb[0] + sb[1] + sb[2] + sb[3];
  __syncthreads();
  const double rn2 = s_rn2;
  const double beta = rn2 / fmax(rz, 1e-300);
#pragma unroll
  for (int i = 0; i < 16; i++) {
    int idx = tid + 256 * i;
    p[idx] = (float)((double)rn[i] + beta * (double)pold[i]);
  }
  if (!tid) {
    scald[1] = rn2;
    if (rn2 < 1e-16) *flag = 1;
  }
}

// out[4096+col] = dv[col] - (A^T yd)[col]   (final re-projection of d)
__global__ __launch_bounds__(256) void k_final_d(const float* __restrict__ A,
                                                 const double* __restrict__ yd,
                                                 const float* __restrict__ dv,
                                                 float* __restrict__ out) {
  __shared__ double ysm[512];
  const int tid = threadIdx.x;
  ysm[tid] = yd[tid]; ysm[tid + 256] = yd[tid + 256];
  __syncthreads();
  const int col = blockIdx.x * 256 + tid;
  double acc = 0.0;
  for (int m = 0; m < Mrows; m++) acc += (double)A[(size_t)m * Ncols + col] * ysm[m];
  out[Ncols + col] = (float)((double)dv[col] - acc);
}

// ---------------------------------------------------------------------------
extern "C" void kernel_launch(void* const* d_in, const int* in_sizes, int n_in,
                              void* d_out, int out_size, void* d_ws, size_t ws_size,
                              hipStream_t stream) {
  const float* A = (const float*)d_in[0];   // 512 x 4096
  const float* b = (const float*)d_in[1];   // 512
  const float* B = (const float*)d_in[2];   // 4096 x 4096
  const float* g = (const float*)d_in[3];   // 4096
  float* out = (float*)d_out;               // x[4096] then d[4096]
  float* ws = (float*)d_ws;

  float* G    = ws;                  // 262144
  float* Xa   = ws + 262144;
  float* Xb   = ws + 524288;
  float* T    = ws + 786432;
  float* P    = ws + 1048576;        // 8 x 262144 partials (AAT); 4 used by NS
  float* Bp   = ws + 3145728;        // 4096 each
  float* PBp  = ws + 3149824;
  float* r    = ws + 3153920;
  float* p    = ws + 3158016;
  float* dv   = ws + 3162112;
  double* t1d = (double*)(ws + 3166208);   // 512 doubles
  double* y0d = (double*)(ws + 3167232);
  double* y1d = (double*)(ws + 3168256);
  double* wd  = (double*)(ws + 3169280);
  double* scald = (double*)(ws + 3170304); // [1]=rz [2]=pPBp [3]=pp
  float* scalf  = (float*)(ws + 3170320);  // [0]=lambda
  int*   flag   = (int*)(ws + 3170324);

  // --- G = A A^T via 8 K-slices + deterministic reduce (G exactly symmetric) ---
  k_aat_part<<<dim3(8, 8, 8), 256, 0, stream>>>(A, P);
  k_red_G<<<256, 256, 0, stream>>>(P, G, scalf, scald, flag);
  k_gersh<<<Mrows, 64, 0, stream>>>(G, scalf);
  k_init_x<<<256, 256, 0, stream>>>(Xa, scalf);

  // --- Newton-Schulz: X <- 2X - X G X, 7 iterations, split-K=4 GEMMs ---
  float* Xcur = Xa;
  float* Xnxt = Xb;
  for (int it = 0; it < 7; it++) {
    k_gemm_t<<<dim3(8, 8, 4), 256, 0, stream>>>(G, Xcur, P, 512, 512, 262144);
    k_red4<<<256, 256, 0, stream>>>(T, P, (const float*)0, 0);     // T = G*X
    k_gemm_t<<<dim3(8, 8, 4), 256, 0, stream>>>(Xcur, T, P, 512, 512, 262144);
    k_red4<<<256, 256, 0, stream>>>(Xnxt, P, Xcur, 1);             // X' = 2X - X*T
    float* tmp = Xcur; Xcur = Xnxt; Xnxt = tmp;
  }

  // --- refinement solve: y = X rhs; 2x { w = rhs - G y; y += X w } (fp64) ---
  #define SOLVE_G(rhsf, rhsd, yv)                                                   \
    k_gmv_d<<<Mrows, 64, 0, stream>>>(Xcur, rhsf, rhsd, (const float*)0,            \
                                      (const double*)0, yv, 0);                     \
    for (int rf = 0; rf < 2; rf++) {                                                \
      k_gmv_d<<<Mrows, 64, 0, stream>>>(G, (const float*)0, yv, rhsf, rhsd, wd, 1); \
      k_gmv_d<<<Mrows, 64, 0, stream>>>(Xcur, (const float*)0, wd, (const float*)0, \
                                        (const double*)0, yv, 2);                   \
    }

  // x = A^T G^{-1} b ; r0 = p = A^T G^{-1}(A g) - g ; rz = ||r0||^2
  k_mv_A<<<Mrows, 256, 0, stream>>>(A, g, t1d, flag, 0);
  SOLVE_G(b, (const double*)0, y0d)
  SOLVE_G((const float*)0, t1d, y1d)
  k_setup_fin<<<16, 256, 0, stream>>>(A, y0d, y1d, g, out, r, p, dv, scald);

  // --- projected CG, 25 iterations, refinement-exact projection each iter ---
  for (int it = 0; it < 25; it++) {
    k_mv_B<<<Ncols, 256, 0, stream>>>(B, p, Bp, scald, flag);    // Bp = B p
    k_mv_A<<<Mrows, 256, 0, stream>>>(A, Bp, t1d, flag, 1);      // t1 = A Bp
    SOLVE_G((const float*)0, t1d, y1d)                           // y1 = G^{-1} t1
    k_pcc2<<<64, 256, 0, stream>>>(A, y1d, Bp, p, PBp, scald, flag);
    k_cg_up<<<1, 256, 0, stream>>>(dv, r, p, PBp, scald, flag);
  }

  // --- d_out = P(dv): strip row-space contamination (fp64-refined solve) ---
  k_mv_A<<<Mrows, 256, 0, stream>>>(A, dv, t1d, flag, 0);
  SOLVE_G((const float*)0, t1d, y1d)
  k_final_d<<<16, 256, 0, stream>>>(A, y1d, dv, out);
  #undef SOLVE_G
}

// Round 6
// 979.651 us; speedup vs baseline: 3.2557x; 1.2217x over previous
//
#include <hip/hip_runtime.h>
#include <hip/hip_bf16.h>

// ProjectedCGCraig on MI355X (gfx950).
//   x = A^T G^{-1} b,  G = A A^T (512x512)
//   d = projected CG (25 iters) with P v = v - A^T G^{-1} A v
// LESSON (R3): per-iteration projection must be refinement-exact (<=1e-9).
//   R = X (I + E + E^2), E = I - G X (fp64)  =>  G R = I - E^3 (~1e-14).
// LESSON (R5): CG scalars must be MEASURED from the stored fp32 vectors each
//   iteration. Carrying rz analytically across iterations accumulates a
//   constant absolute offset that dominates once the residual stagnates ->
//   alpha inconsistency -> blowup. So k_pcc3 re-measures rr = ||r||^2 fresh;
//   the rn2 identity is used only within-iteration (for beta).
// M=512, N=4096 fixed.

#define Mrows 512
#define Ncols 4096

__device__ __forceinline__ float waveReduceF(float v) {
#pragma unroll
  for (int off = 32; off; off >>= 1) v += __shfl_down(v, off, 64);
  return v;
}
__device__ __forceinline__ double waveReduceD(double v) {
#pragma unroll
  for (int off = 32; off; off >>= 1) v += __shfl_down(v, off, 64);
  return v;
}

// ---------------------------------------------------------------------------
// Generic tiled fp32 GEMM: C = Am[M x K] * Bm[K x N]. 64x64 tile, 4x4 micro,
// 256 threads. grid (N/64, M/64, S): K-split S, slice z -> Cp + z*part_stride.
// ---------------------------------------------------------------------------
__global__ __launch_bounds__(256) void k_gemm_t(const float* __restrict__ Am,
                                                const float* __restrict__ Bm,
                                                float* __restrict__ Cp,
                                                int K, int N, int part_stride) {
  __shared__ float At[32][68];
  __shared__ float Bt[32][68];
  const int tid = threadIdx.x;
  const int tx = tid & 15, ty = tid >> 4;
  const int bj = blockIdx.x * 64, bi = blockIdx.y * 64;
  const int Klen = K / gridDim.z;
  const int Kb = blockIdx.z * Klen;
  float c0x = 0.f, c0y = 0.f, c0z = 0.f, c0w = 0.f;
  float c1x = 0.f, c1y = 0.f, c1z = 0.f, c1w = 0.f;
  float c2x = 0.f, c2y = 0.f, c2z = 0.f, c2w = 0.f;
  float c3x = 0.f, c3y = 0.f, c3z = 0.f, c3w = 0.f;
  for (int k0 = 0; k0 < Klen; k0 += 32) {
#pragma unroll
    for (int l = 0; l < 2; l++) {
      int f = tid + l * 256;
      int ar = f >> 3, ak = f & 7;
      const float4 av = *(const float4*)&Am[(size_t)(bi + ar) * K + Kb + k0 + ak * 4];
      At[ak * 4 + 0][ar] = av.x; At[ak * 4 + 1][ar] = av.y;
      At[ak * 4 + 2][ar] = av.z; At[ak * 4 + 3][ar] = av.w;
    }
#pragma unroll
    for (int l = 0; l < 2; l++) {
      int f = tid + l * 256;
      int br = f >> 4, bc = f & 15;
      *(float4*)&Bt[br][bc * 4] =
          *(const float4*)&Bm[(size_t)(Kb + k0 + br) * N + bj + bc * 4];
    }
    __syncthreads();
#pragma unroll
    for (int kk = 0; kk < 32; kk++) {
      float4 a = *(float4*)&At[kk][ty * 4];
      float4 b = *(float4*)&Bt[kk][tx * 4];
      c0x += a.x * b.x; c0y += a.x * b.y; c0z += a.x * b.z; c0w += a.x * b.w;
      c1x += a.y * b.x; c1y += a.y * b.y; c1z += a.y * b.z; c1w += a.y * b.w;
      c2x += a.z * b.x; c2y += a.z * b.y; c2z += a.z * b.z; c2w += a.z * b.w;
      c3x += a.w * b.x; c3y += a.w * b.y; c3z += a.w * b.z; c3w += a.w * b.w;
    }
    __syncthreads();
  }
  float* Co = Cp + (size_t)blockIdx.z * part_stride;
  size_t o = (size_t)(bi + ty * 4) * N + bj + tx * 4;
  *(float4*)&Co[o]         = make_float4(c0x, c0y, c0z, c0w);
  *(float4*)&Co[o + N]     = make_float4(c1x, c1y, c1z, c1w);
  *(float4*)&Co[o + 2 * N] = make_float4(c2x, c2y, c2z, c2w);
  *(float4*)&Co[o + 3 * N] = make_float4(c3x, c3y, c3z, c3w);
}

// ---------------------------------------------------------------------------
// Partial AAT: slice bz = A[bi..][Kb..] * A[bj..][Kb..]^T, K-slice 512. (8,8,8).
// ---------------------------------------------------------------------------
__global__ __launch_bounds__(256) void k_aat_part(const float* __restrict__ A,
                                                  float* __restrict__ P) {
  __shared__ float At[32][68];
  __shared__ float Bt[32][68];
  const int tid = threadIdx.x;
  const int tx = tid & 15, ty = tid >> 4;
  const int bj = blockIdx.x * 64, bi = blockIdx.y * 64;
  const int Kb = blockIdx.z * 512;
  float c0x = 0.f, c0y = 0.f, c0z = 0.f, c0w = 0.f;
  float c1x = 0.f, c1y = 0.f, c1z = 0.f, c1w = 0.f;
  float c2x = 0.f, c2y = 0.f, c2z = 0.f, c2w = 0.f;
  float c3x = 0.f, c3y = 0.f, c3z = 0.f, c3w = 0.f;
  for (int k0 = 0; k0 < 512; k0 += 32) {
#pragma unroll
    for (int l = 0; l < 2; l++) {
      int f = tid + l * 256;
      int ar = f >> 3, ak = f & 7;
      const float4 av = *(const float4*)&A[(size_t)(bi + ar) * Ncols + Kb + k0 + ak * 4];
      At[ak * 4 + 0][ar] = av.x; At[ak * 4 + 1][ar] = av.y;
      At[ak * 4 + 2][ar] = av.z; At[ak * 4 + 3][ar] = av.w;
      const float4 bv = *(const float4*)&A[(size_t)(bj + ar) * Ncols + Kb + k0 + ak * 4];
      Bt[ak * 4 + 0][ar] = bv.x; Bt[ak * 4 + 1][ar] = bv.y;
      Bt[ak * 4 + 2][ar] = bv.z; Bt[ak * 4 + 3][ar] = bv.w;
    }
    __syncthreads();
#pragma unroll
    for (int kk = 0; kk < 32; kk++) {
      float4 a = *(float4*)&At[kk][ty * 4];
      float4 b = *(float4*)&Bt[kk][tx * 4];
      c0x += a.x * b.x; c0y += a.x * b.y; c0z += a.x * b.z; c0w += a.x * b.w;
      c1x += a.y * b.x; c1y += a.y * b.y; c1z += a.y * b.z; c1w += a.y * b.w;
      c2x += a.z * b.x; c2y += a.z * b.y; c2z += a.z * b.z; c2w += a.z * b.w;
      c3x += a.w * b.x; c3y += a.w * b.y; c3z += a.w * b.z; c3w += a.w * b.w;
    }
    __syncthreads();
  }
  float* Co = P + (size_t)blockIdx.z * 262144;
  size_t o = (size_t)(bi + ty * 4) * Mrows + bj + tx * 4;
  *(float4*)&Co[o]             = make_float4(c0x, c0y, c0z, c0w);
  *(float4*)&Co[o + Mrows]     = make_float4(c1x, c1y, c1z, c1w);
  *(float4*)&Co[o + 2 * Mrows] = make_float4(c2x, c2y, c2z, c2w);
  *(float4*)&Co[o + 3 * Mrows] = make_float4(c3x, c3y, c3z, c3w);
}

// G = sum of 8 partials; zero scalf[0]/flag.
__global__ void k_red_G(const float* __restrict__ P, float* __restrict__ G,
                        float* __restrict__ scalf, int* __restrict__ flag) {
  int i4 = blockIdx.x * 256 + threadIdx.x;
  float4 s = ((const float4*)P)[i4];
#pragma unroll
  for (int p = 1; p < 8; p++) {
    float4 v = ((const float4*)(P + (size_t)p * 262144))[i4];
    s.x += v.x; s.y += v.y; s.z += v.z; s.w += v.w;
  }
  ((float4*)G)[i4] = s;
  if (i4 == 0) { scalf[0] = 0.f; flag[0] = 0; }
}

// mode 0: dst = sum_{p<8} P_p ; mode 1: dst = 2*D - sum
__global__ void k_red8(float* __restrict__ dst, const float* __restrict__ P,
                       const float* __restrict__ D, int mode) {
  int i4 = blockIdx.x * 256 + threadIdx.x;
  float4 s = ((const float4*)P)[i4];
#pragma unroll
  for (int p = 1; p < 8; p++) {
    float4 v = ((const float4*)(P + (size_t)p * 262144))[i4];
    s.x += v.x; s.y += v.y; s.z += v.z; s.w += v.w;
  }
  if (mode == 1) {
    float4 d = ((const float4*)D)[i4];
    s = make_float4(2.f * d.x - s.x, 2.f * d.y - s.y, 2.f * d.z - s.z, 2.f * d.w - s.w);
  }
  ((float4*)dst)[i4] = s;
}

// Gershgorin bound: scalf[0] = max_i sum_j |G[i][j]|
__global__ void k_gersh(const float* __restrict__ G, float* __restrict__ scalf) {
  const int m = blockIdx.x, tid = threadIdx.x;
  float acc = 0.f;
  for (int j = tid; j < Mrows; j += 64) acc += fabsf(G[m * Mrows + j]);
  acc = waveReduceF(acc);
  if (tid == 0) atomicMax((int*)&scalf[0], __float_as_int(acc));
}

// X0 = (2/lambda) * I
__global__ void k_init_x(float* __restrict__ X, const float* __restrict__ scalf) {
  float inv = 2.f / scalf[0];
  int idx = blockIdx.x * blockDim.x + threadIdx.x;
#pragma unroll
  for (int l = 0; l < 4; l++) {
    int e = idx + l * 65536;
    X[e] = ((e >> 9) == (e & 511)) ? inv : 0.f;
  }
}

// ---------------------------------------------------------------------------
// fp64 512x512 GEMMs for R = X (I + E + E^2).  Grid (16,16), 256 thr, 2x2.
// ---------------------------------------------------------------------------
// E = I - G*X  (G,X fp32 in; E fp64 out)
__global__ __launch_bounds__(256) void k_gemm_E(const float* __restrict__ G,
                                                const float* __restrict__ X,
                                                double* __restrict__ E) {
  __shared__ float Gs[32][33], Xs[32][33];
  const int tid = threadIdx.x;
  const int tx = tid & 15, ty = tid >> 4;
  const int bi = blockIdx.y * 32, bj = blockIdx.x * 32;
  const int r0 = ty * 2, c0 = tx * 2;
  double a00 = 0, a01 = 0, a10 = 0, a11 = 0;
  for (int k0 = 0; k0 < Mrows; k0 += 32) {
#pragma unroll
    for (int l = 0; l < 4; l++) {
      int e = tid + l * 256;
      int rr = e >> 5, cc = e & 31;
      Gs[rr][cc] = G[(size_t)(bi + rr) * Mrows + k0 + cc];
      Xs[rr][cc] = X[(size_t)(k0 + rr) * Mrows + bj + cc];
    }
    __syncthreads();
#pragma unroll
    for (int kk = 0; kk < 32; kk++) {
      double g0 = Gs[r0][kk], g1 = Gs[r0 + 1][kk];
      double x0 = Xs[kk][c0], x1 = Xs[kk][c0 + 1];
      a00 += g0 * x0; a01 += g0 * x1; a10 += g1 * x0; a11 += g1 * x1;
    }
    __syncthreads();
  }
  size_t o = (size_t)(bi + r0) * Mrows + bj + c0;
  E[o] = ((bi + r0) == (bj + c0) ? 1.0 : 0.0) - a00;
  E[o + 1] = ((bi + r0) == (bj + c0 + 1) ? 1.0 : 0.0) - a01;
  E[o + Mrows] = ((bi + r0 + 1) == (bj + c0) ? 1.0 : 0.0) - a10;
  E[o + Mrows + 1] = ((bi + r0 + 1) == (bj + c0 + 1) ? 1.0 : 0.0) - a11;
}

// U = X*E  (X fp32, E fp64)
__global__ __launch_bounds__(256) void k_gemm_XE(const float* __restrict__ X,
                                                 const double* __restrict__ E,
                                                 double* __restrict__ U) {
  __shared__ float Xs[32][33];
  __shared__ double Es[32][33];
  const int tid = threadIdx.x;
  const int tx = tid & 15, ty = tid >> 4;
  const int bi = blockIdx.y * 32, bj = blockIdx.x * 32;
  const int r0 = ty * 2, c0 = tx * 2;
  double a00 = 0, a01 = 0, a10 = 0, a11 = 0;
  for (int k0 = 0; k0 < Mrows; k0 += 32) {
#pragma unroll
    for (int l = 0; l < 4; l++) {
      int e = tid + l * 256;
      int rr = e >> 5, cc = e & 31;
      Xs[rr][cc] = X[(size_t)(bi + rr) * Mrows + k0 + cc];
      Es[rr][cc] = E[(size_t)(k0 + rr) * Mrows + bj + cc];
    }
    __syncthreads();
#pragma unroll
    for (int kk = 0; kk < 32; kk++) {
      double x0 = Xs[r0][kk], x1 = Xs[r0 + 1][kk];
      double e0 = Es[kk][c0], e1 = Es[kk][c0 + 1];
      a00 += x0 * e0; a01 += x0 * e1; a10 += x1 * e0; a11 += x1 * e1;
    }
    __syncthreads();
  }
  size_t o = (size_t)(bi + r0) * Mrows + bj + c0;
  U[o] = a00; U[o + 1] = a01; U[o + Mrows] = a10; U[o + Mrows + 1] = a11;
}

// R = Xf + U + U*E  (U,E fp64; Xf fp32 elementwise in epilogue)
__global__ __launch_bounds__(256) void k_gemm_UER(const double* __restrict__ U,
                                                  const double* __restrict__ E,
                                                  const float* __restrict__ Xf,
                                                  double* __restrict__ R) {
  __shared__ double Us[32][33];
  __shared__ double Es[32][33];
  const int tid = threadIdx.x;
  const int tx = tid & 15, ty = tid >> 4;
  const int bi = blockIdx.y * 32, bj = blockIdx.x * 32;
  const int r0 = ty * 2, c0 = tx * 2;
  double a00 = 0, a01 = 0, a10 = 0, a11 = 0;
  for (int k0 = 0; k0 < Mrows; k0 += 32) {
#pragma unroll
    for (int l = 0; l < 4; l++) {
      int e = tid + l * 256;
      int rr = e >> 5, cc = e & 31;
      Us[rr][cc] = U[(size_t)(bi + rr) * Mrows + k0 + cc];
      Es[rr][cc] = E[(size_t)(k0 + rr) * Mrows + bj + cc];
    }
    __syncthreads();
#pragma unroll
    for (int kk = 0; kk < 32; kk++) {
      double u0 = Us[r0][kk], u1 = Us[r0 + 1][kk];
      double e0 = Es[kk][c0], e1 = Es[kk][c0 + 1];
      a00 += u0 * e0; a01 += u0 * e1; a10 += u1 * e0; a11 += u1 * e1;
    }
    __syncthreads();
  }
  size_t o = (size_t)(bi + r0) * Mrows + bj + c0;
  R[o] = (double)Xf[o] + U[o] + a00;
  R[o + 1] = (double)Xf[o + 1] + U[o + 1] + a01;
  R[o + Mrows] = (double)Xf[o + Mrows] + U[o + Mrows] + a10;
  R[o + Mrows + 1] = (double)Xf[o + Mrows + 1] + U[o + Mrows + 1] + a11;
}

// ---------------------------------------------------------------------------
// y = R * rhs (fp64 matvec, 512 blocks x 64 thr). rhs fp32 or fp64 ptr.
// ---------------------------------------------------------------------------
__global__ __launch_bounds__(64) void k_solveR(const double* __restrict__ R,
                                               const float* __restrict__ rhs_f,
                                               const double* __restrict__ rhs_d,
                                               double* __restrict__ y,
                                               const int* __restrict__ flag, int chk) {
  if (chk && *flag) return;
  const int m = blockIdx.x, t = threadIdx.x;
  const double2* Rr = (const double2*)(R + (size_t)m * Mrows);
  double acc = 0.0;
#pragma unroll
  for (int i = 0; i < 4; i++) {
    int i2 = t + 64 * i;
    double2 a = Rr[i2];
    double x0, x1;
    if (rhs_f) { x0 = rhs_f[i2 * 2]; x1 = rhs_f[i2 * 2 + 1]; }
    else       { x0 = rhs_d[i2 * 2]; x1 = rhs_d[i2 * 2 + 1]; }
    acc += a.x * x0 + a.y * x1;
  }
  acc = waveReduceD(acc);
  if (t == 0) y[m] = acc;
}

// t1d[m] = dot(A[m,:], v) fp64, row length 4096. 512 blocks x 256.
__global__ __launch_bounds__(256) void k_mv_A(const float* __restrict__ Mat,
                                              const float* __restrict__ v,
                                              double* __restrict__ t1d,
                                              const int* __restrict__ flag, int chk) {
  if (chk && *flag) return;
  const int m = blockIdx.x, tid = threadIdx.x;
  const float4* Mr = (const float4*)(Mat + (size_t)m * Ncols);
  const float4* v4 = (const float4*)v;
  double acc = 0.0;
#pragma unroll
  for (int i = 0; i < 4; i++) {
    float4 a = Mr[tid + 256 * i];
    float4 x = v4[tid + 256 * i];
    acc += (double)a.x * x.x + (double)a.y * x.y + (double)a.z * x.z + (double)a.w * x.w;
  }
  __shared__ double sb[4];
  acc = waveReduceD(acc);
  const int lane = tid & 63, wid = tid >> 6;
  if (!lane) sb[wid] = acc;
  __syncthreads();
  if (!tid) t1d[m] = sb[0] + sb[1] + sb[2] + sb[3];
}

// Bp[m] = dot(B[m,:], p). 4096 blocks x 256.
__global__ __launch_bounds__(256) void k_mv_B(const float* __restrict__ B,
                                              const float* __restrict__ p,
                                              float* __restrict__ Bp,
                                              const int* __restrict__ flag) {
  if (*flag) return;
  const int m = blockIdx.x, tid = threadIdx.x;
  const float4* Mr = (const float4*)(B + (size_t)m * Ncols);
  const float4* v4 = (const float4*)p;
  double acc = 0.0;
#pragma unroll
  for (int i = 0; i < 4; i++) {
    float4 a = Mr[tid + 256 * i];
    float4 x = v4[tid + 256 * i];
    acc += (double)a.x * x.x + (double)a.y * x.y + (double)a.z * x.z + (double)a.w * x.w;
  }
  __shared__ double sb[4];
  acc = waveReduceD(acc);
  const int lane = tid & 63, wid = tid >> 6;
  if (!lane) sb[wid] = acc;
  __syncthreads();
  if (!tid) Bp[m] = (float)(sb[0] + sb[1] + sb[2] + sb[3]);
}

// ---------------------------------------------------------------------------
// Setup outputs + CG init (grid 16 x 256):
//   x = A^T y0 -> out[0..4096) ; r = p = A^T y1 - g ; dv = 0
// ---------------------------------------------------------------------------
__global__ __launch_bounds__(256) void k_setup_fin(const float* __restrict__ A,
                                                   const double* __restrict__ y0d,
                                                   const double* __restrict__ y1d,
                                                   const float* __restrict__ g,
                                                   float* __restrict__ out,
                                                   float* __restrict__ r,
                                                   float* __restrict__ p,
                                                   float* __restrict__ dv) {
  __shared__ double y0s[512], y1s[512];
  const int tid = threadIdx.x;
  y0s[tid] = y0d[tid]; y0s[tid + 256] = y0d[tid + 256];
  y1s[tid] = y1d[tid]; y1s[tid + 256] = y1d[tid + 256];
  __syncthreads();
  const int col = blockIdx.x * 256 + tid;
  double xa = 0.0, ra = 0.0;
  for (int m = 0; m < Mrows; m++) {
    double av = (double)A[(size_t)m * Ncols + col];
    xa += av * y0s[m];
    ra += av * y1s[m];
  }
  out[col] = (float)xa;
  float rv = (float)(ra - (double)g[col]);
  r[col] = rv; p[col] = rv; dv[col] = 0.f;
}

// ---------------------------------------------------------------------------
// PBp = Bp - A^T y ; block-partial dots (dot-major dotbuf[dot*64 + block]):
//   {0: p.PBp, 1: p.p, 2: r.PBp, 3: PBp.PBp, 4: r.r}
// Grid 64 x 256 (64 cols/block, m 4-split). ALL dots measured fresh from the
// stored fp32 vectors (LESSON R5).
// ---------------------------------------------------------------------------
__global__ __launch_bounds__(256) void k_pcc3(const float* __restrict__ A,
                                              const double* __restrict__ yd,
                                              const float* __restrict__ Bp,
                                              const float* __restrict__ p,
                                              const float* __restrict__ r,
                                              float* __restrict__ PBp,
                                              double* __restrict__ dotbuf,
                                              const int* __restrict__ flag) {
  if (*flag) return;
  __shared__ double ysm[512];
  __shared__ double part[4][64];
  const int tid = threadIdx.x;
  ysm[tid] = yd[tid]; ysm[tid + 256] = yd[tid + 256];
  __syncthreads();
  const int cl = tid & 63;
  const int q = tid >> 6;
  const int col = blockIdx.x * 64 + cl;
  double acc = 0.0;
  for (int m = q * 128; m < q * 128 + 128; m++)
    acc += (double)A[(size_t)m * Ncols + col] * ysm[m];
  part[q][cl] = acc;
  __syncthreads();
  if (q == 0) {
    double s = part[0][cl] + part[1][cl] + part[2][cl] + part[3][cl];
    double pb = (double)Bp[col] - s;
    PBp[col] = (float)pb;
    double pi = (double)p[col];
    double ri = (double)r[col];
    double d0 = waveReduceD(pi * pb);
    double d1 = waveReduceD(pi * pi);
    double d2 = waveReduceD(ri * pb);
    double d3 = waveReduceD(pb * pb);
    double d4 = waveReduceD(ri * ri);
    if (cl == 0) {
      dotbuf[0 * 64 + blockIdx.x] = d0;
      dotbuf[1 * 64 + blockIdx.x] = d1;
      dotbuf[2 * 64 + blockIdx.x] = d2;
      dotbuf[3 * 64 + blockIdx.x] = d3;
      dotbuf[4 * 64 + blockIdx.x] = d4;
    }
  }
}

// ---------------------------------------------------------------------------
// CG update (16 blocks x 256): ALL scalars fresh from dotbuf.
//   rr = |r|^2 (fresh) ; alpha = rr/pPBp ; rn2 = rr - 2a(r.PBp) + a^2|PBp|^2
//   (exact fp64 value of the new residual norm, used only within-iteration);
//   beta = rn2/rr ; dv += a p ; r' = r - a PBp ; p' = r' + b p.
// No carried scalar state across iterations.
// ---------------------------------------------------------------------------
__global__ __launch_bounds__(256) void k_vup(float* __restrict__ dv,
                                             float* __restrict__ r,
                                             float* __restrict__ p,
                                             const float* __restrict__ PBp,
                                             const double* __restrict__ dotbuf,
                                             int* __restrict__ flag) {
  if (*flag) return;
  __shared__ double sd[5];
  const int tid = threadIdx.x;
  const int w = tid >> 6, l = tid & 63;
  double v = dotbuf[w * 64 + l];
  v = waveReduceD(v);
  if (l == 0) sd[w] = v;
  if (w == 0) {
    double v4 = dotbuf[4 * 64 + l];
    v4 = waveReduceD(v4);
    if (l == 0) sd[4] = v4;
  }
  __syncthreads();
  const double pPBp = sd[0], pp = sd[1], rPBp = sd[2], PBp2 = sd[3], rr = sd[4];
  const bool bad = (pPBp <= 1e-6 * pp);
  if (bad) { if (blockIdx.x == 0 && tid == 0) *flag = 1; return; }
  const double alpha = rr / fmax(pPBp, 1e-300);
  double rn2 = rr - 2.0 * alpha * rPBp + alpha * alpha * PBp2;
  rn2 = fmax(rn2, 0.0);
  const double beta = rn2 / fmax(rr, 1e-300);
  const int idx = blockIdx.x * 256 + tid;
  const double pi = (double)p[idx];
  dv[idx] = (float)((double)dv[idx] + alpha * pi);
  const double rv = (double)r[idx] - alpha * (double)PBp[idx];
  r[idx] = (float)rv;
  p[idx] = (float)(rv + beta * pi);
  if (blockIdx.x == 0 && tid == 0) {
    if (rn2 < 1e-16) *flag = 1;
  }
}

// out[4096+col] = dv[col] - (A^T yd)[col]   (final re-projection of d)
__global__ __launch_bounds__(256) void k_final_d(const float* __restrict__ A,
                                                 const double* __restrict__ yd,
                                                 const float* __restrict__ dv,
                                                 float* __restrict__ out) {
  __shared__ double ysm[512];
  const int tid = threadIdx.x;
  ysm[tid] = yd[tid]; ysm[tid + 256] = yd[tid + 256];
  __syncthreads();
  const int col = blockIdx.x * 256 + tid;
  double acc = 0.0;
  for (int m = 0; m < Mrows; m++) acc += (double)A[(size_t)m * Ncols + col] * ysm[m];
  out[Ncols + col] = (float)((double)dv[col] - acc);
}

// ---------------------------------------------------------------------------
extern "C" void kernel_launch(void* const* d_in, const int* in_sizes, int n_in,
                              void* d_out, int out_size, void* d_ws, size_t ws_size,
                              hipStream_t stream) {
  const float* A = (const float*)d_in[0];   // 512 x 4096
  const float* b = (const float*)d_in[1];   // 512
  const float* B = (const float*)d_in[2];   // 4096 x 4096
  const float* g = (const float*)d_in[3];   // 4096
  float* out = (float*)d_out;               // x[4096] then d[4096]
  float* ws = (float*)d_ws;

  float*  G   = ws;                         // 262144 floats
  float*  Xa  = ws + 262144;
  float*  Xb  = ws + 524288;
  float*  T   = ws + 786432;
  float*  P   = ws + 1048576;               // 8 x 262144 (AAT / NS partials)
  double* Ed  = (double*)(ws + 1048576);    // aliases P (used after NS only)
  double* Ud  = (double*)(ws + 1572864);    // aliases P
  double* Rd  = (double*)(ws + 3145728);    // 512x512 fp64 = 524288 floats
  float*  Bp  = ws + 3670016;               // 4096 each
  float*  PBp = ws + 3674112;
  float*  r   = ws + 3678208;
  float*  p   = ws + 3682304;
  float*  dv  = ws + 3686400;
  double* t1d = (double*)(ws + 3690496);    // 512 doubles
  double* y0d = (double*)(ws + 3691520);
  double* y1d = (double*)(ws + 3692544);
  double* dotbuf = (double*)(ws + 3693568); // 320 doubles (5 dots x 64 blocks)
  float*  scalf  = (float*)(ws + 3694208);  // [0] = lambda
  int*    flag   = (int*)(ws + 3694212);

  // --- G = A A^T (8 K-slices + deterministic reduce: exactly symmetric) ---
  k_aat_part<<<dim3(8, 8, 8), 256, 0, stream>>>(A, P);
  k_red_G<<<256, 256, 0, stream>>>(P, G, scalf, flag);
  k_gersh<<<Mrows, 64, 0, stream>>>(G, scalf);
  k_init_x<<<256, 256, 0, stream>>>(Xa, scalf);

  // --- Newton-Schulz: X <- 2X - X G X, 7 iterations, split-K=8 GEMMs ---
  float* Xcur = Xa;
  float* Xnxt = Xb;
  for (int it = 0; it < 7; it++) {
    k_gemm_t<<<dim3(8, 8, 8), 256, 0, stream>>>(G, Xcur, P, 512, 512, 262144);
    k_red8<<<256, 256, 0, stream>>>(T, P, (const float*)0, 0);     // T = G*X
    k_gemm_t<<<dim3(8, 8, 8), 256, 0, stream>>>(Xcur, T, P, 512, 512, 262144);
    k_red8<<<256, 256, 0, stream>>>(Xnxt, P, Xcur, 1);             // X' = 2X - X*T
    float* tmp = Xcur; Xcur = Xnxt; Xnxt = tmp;
  }

  // --- R = X (I + E + E^2), E = I - G X : G*R = I - E^3 (fp64) ---
  k_gemm_E<<<dim3(16, 16), 256, 0, stream>>>(G, Xcur, Ed);
  k_gemm_XE<<<dim3(16, 16), 256, 0, stream>>>(Xcur, Ed, Ud);
  k_gemm_UER<<<dim3(16, 16), 256, 0, stream>>>(Ud, Ed, Xcur, Rd);

  // --- x = A^T R b ; r0 = p = A^T R (A g) - g ---
  k_mv_A<<<Mrows, 256, 0, stream>>>(A, g, t1d, flag, 0);
  k_solveR<<<Mrows, 64, 0, stream>>>(Rd, b, (const double*)0, y0d, flag, 0);
  k_solveR<<<Mrows, 64, 0, stream>>>(Rd, (const float*)0, t1d, y1d, flag, 0);
  k_setup_fin<<<16, 256, 0, stream>>>(A, y0d, y1d, g, out, r, p, dv);

  // --- projected CG, 25 iterations (5 kernels each, no carried scalars) ---
  for (int it = 0; it < 25; it++) {
    k_mv_B<<<Ncols, 256, 0, stream>>>(B, p, Bp, flag);
    k_mv_A<<<Mrows, 256, 0, stream>>>(A, Bp, t1d, flag, 1);
    k_solveR<<<Mrows, 64, 0, stream>>>(Rd, (const float*)0, t1d, y1d, flag, 1);
    k_pcc3<<<64, 256, 0, stream>>>(A, y1d, Bp, p, r, PBp, dotbuf, flag);
    k_vup<<<16, 256, 0, stream>>>(dv, r, p, PBp, dotbuf, flag);
  }

  // --- d_out = P(dv): strip row-space contamination ---
  k_mv_A<<<Mrows, 256, 0, stream>>>(A, dv, t1d, flag, 0);
  k_solveR<<<Mrows, 64, 0, stream>>>(Rd, (const float*)0, t1d, y1d, flag, 0);
  k_final_d<<<16, 256, 0, stream>>>(A, y1d, dv, out);
}